// Round 2
// baseline (190.706 us; speedup 1.0000x reference)
//
#include <hip/hip_runtime.h>
#include <hip/hip_bf16.h>
#include <stdint.h>

#define B_ 2
#define C_ 256
#define H_ 96
#define W_ 96
#define HW_ (H_*W_)

typedef _Float16 h2 __attribute__((ext_vector_type(2)));
typedef _Float16 h8 __attribute__((ext_vector_type(8)));

union H8U { h8 v; h2 h[4]; };

__device__ __forceinline__ float dot2f(h2 a, h2 b, float c) {
#if __has_builtin(__builtin_amdgcn_fdot2)
  return __builtin_amdgcn_fdot2(a, b, c, false);
#else
  return c + (float)a[0] * (float)b[0] + (float)a[1] * (float)b[1];
#endif
}

// ---------- (B, C, HW) f32  ->  (B, HW, C) f16 tile transpose (+scale) ----------
__global__ __launch_bounds__(256) void k_transpose(const float* __restrict__ in,
                                                   _Float16* __restrict__ out,
                                                   float scale) {
  __shared__ float t[32][33];
  const int b = blockIdx.z;
  const int p0 = blockIdx.x * 32, c0 = blockIdx.y * 32;
  const int tx = threadIdx.x, ty = threadIdx.y;
  const float* src = in + ((size_t)b * C_ + c0) * HW_ + p0;
#pragma unroll
  for (int i = 0; i < 4; ++i)
    t[ty + 8 * i][tx] = src[(size_t)(ty + 8 * i) * HW_ + tx];
  __syncthreads();
  _Float16* dst = out + ((size_t)b * HW_ + p0) * C_ + c0;
#pragma unroll
  for (int i = 0; i < 4; ++i)
    dst[(size_t)(ty + 8 * i) * C_ + tx] = (_Float16)(t[tx][ty + 8 * i] * scale);
}

// ---------- 2x2 avg pool on (B, h, w, C) f16 ----------
__global__ __launch_bounds__(256) void k_pool(const _Float16* __restrict__ in,
                                              _Float16* __restrict__ out,
                                              int hin, int win) {
  const int wout = win >> 1, hout = hin >> 1;
  int idx = blockIdx.x;
  const int X = idx % wout; idx /= wout;
  const int Y = idx % hout; const int b = idx / hout;
  const int c = threadIdx.x;
  const _Float16* p = in + (((size_t)b * hin + 2 * Y) * win + 2 * X) * C_ + c;
  const size_t rs = (size_t)win * C_;
  float v = (float)p[0] + (float)p[C_] + (float)p[rs] + (float)p[rs + C_];
  out[(((size_t)b * hout + Y) * wout + X) * C_ + c] = (_Float16)(v * 0.25f);
}

// workspace byte layout: [zero page 512][f1t][L0][L1][L2][L3]
#define F1OFF 512u
#define L0OFF 9437696u
#define L1OFF 18874880u
#define L2OFF 21234176u
#define L3OFF 21824000u

// ---------- main: per-pixel windowed dot products + bilinear combine ----------
__global__ __launch_bounds__(256) void k_corr(const char* __restrict__ ws,
                                              const float* __restrict__ cent,
                                              float* __restrict__ out) {
  __shared__ float dl[4][112];
  __shared__ uint32_t ofs[4][104];
  const int wid  = threadIdx.x >> 6;
  const int lane = threadIdx.x & 63;
  const int cg   = lane & 7;           // channel subgroup (32 ch = 4x h8)
  const int pg   = lane >> 3;          // position subgroup

  // XCD-aware swizzle: XCDs 0-3 -> batch 0, XCDs 4-7 -> batch 1.
  const int g    = blockIdx.x;
  const int xcd  = g & 7;
  const int slot = g >> 3;
  const int b    = xcd >> 2;
  const int ib   = slot * 4 + (xcd & 3);
  const int yx   = ib * 4 + wid;
  const int pix  = b * HW_ + yx;

  const float cx = cent[(size_t)(b * 2 + 0) * HW_ + yx];
  const float cy = cent[(size_t)(b * 2 + 1) * HW_ + yx];

  // f1 (pre-scaled by 1/16 in transpose) as 16 packed h2 regs
  h2 f1h[16];
  {
    const h8* fp = (const h8*)(ws + F1OFF + (size_t)pix * 512 + cg * 16);
#pragma unroll
    for (int it = 0; it < 4; ++it) {
      H8U u; u.v = fp[it * 8];
      f1h[it * 4 + 0] = u.h[0]; f1h[it * 4 + 1] = u.h[1];
      f1h[it * 4 + 2] = u.h[2]; f1h[it * 4 + 3] = u.h[3];
    }
  }

  constexpr uint32_t LB[4] = {L0OFF, L1OFF, L2OFF, L3OFF};
  constexpr uint32_t PB[4] = {4718592u, 1179648u, 294912u, 73728u};

#pragma unroll
  for (int lvl = 0; lvl < 4; ++lvl) {
    const int hl = H_ >> lvl, wl = W_ >> lvl;
    const float sc  = 1.0f / (float)(1 << lvl);
    const float cxl = cx * sc, cyl = cy * sc;
    const float fx = floorf(cxl), fy = floorf(cyl);
    const int X0 = (int)fx - 4, Y0 = (int)fy - 4;
    const float wx1 = cxl - fx, wy1 = cyl - fy;
    const float wx0 = 1.0f - wx1, wy0 = 1.0f - wy1;

    // build per-wave offset table: 100 positions (+4 phantom), zero page if OOB
    const uint32_t lbase = LB[lvl] + (uint32_t)b * PB[lvl];
#pragma unroll
    for (int r = 0; r < 2; ++r) {
      const int p = r * 64 + lane;
      if (p < 104) {
        const int prow = p / 10, pcol = p - prow * 10;
        const int yy = Y0 + prow, xx = X0 + pcol;
        const bool valid = (p < 100) & (yy >= 0) & (yy < hl) & (xx >= 0) & (xx < wl);
        ofs[wid][p] = valid ? (lbase + ((uint32_t)(yy * wl + xx) << 9)) : 0u;
      }
    }
    __syncthreads();

    // 100 window positions, 8 per iteration; 32 channels per lane via packed dot2
    for (int gq = 0; gq < 13; ++gq) {
      const uint32_t off = ofs[wid][gq * 8 + pg] + (uint32_t)cg * 16;
      const h8* hp = (const h8*)(ws + off);
      H8U u0, u1, u2, u3;
      u0.v = hp[0]; u1.v = hp[8]; u2.v = hp[16]; u3.v = hp[24];
      float a0 = 0.f, a1 = 0.f, a2 = 0.f, a3 = 0.f;
      a0 = dot2f(u0.h[0], f1h[0],  a0); a0 = dot2f(u0.h[1], f1h[1],  a0);
      a0 = dot2f(u0.h[2], f1h[2],  a0); a0 = dot2f(u0.h[3], f1h[3],  a0);
      a1 = dot2f(u1.h[0], f1h[4],  a1); a1 = dot2f(u1.h[1], f1h[5],  a1);
      a1 = dot2f(u1.h[2], f1h[6],  a1); a1 = dot2f(u1.h[3], f1h[7],  a1);
      a2 = dot2f(u2.h[0], f1h[8],  a2); a2 = dot2f(u2.h[1], f1h[9],  a2);
      a2 = dot2f(u2.h[2], f1h[10], a2); a2 = dot2f(u2.h[3], f1h[11], a2);
      a3 = dot2f(u3.h[0], f1h[12], a3); a3 = dot2f(u3.h[1], f1h[13], a3);
      a3 = dot2f(u3.h[2], f1h[14], a3); a3 = dot2f(u3.h[3], f1h[15], a3);
      float acc = (a0 + a1) + (a2 + a3);
      acc += __shfl_xor(acc, 1);
      acc += __shfl_xor(acc, 2);
      acc += __shfl_xor(acc, 4);
      const int p = gq * 8 + pg;
      if (cg == 0 && p < 100) dl[wid][p] = acc;
    }
    __syncthreads();

    // separable bilinear combine + store
#pragma unroll
    for (int r = 0; r < 2; ++r) {
      const int o = r * 64 + lane;
      if (o < 81) {
        const int a = o / 9, bq = o - a * 9;
        const float* d = dl[wid];
        const float d00 = d[bq * 10 + a],      d10 = d[bq * 10 + a + 1];
        const float d01 = d[bq * 10 + a + 10], d11 = d[bq * 10 + a + 11];
        const float v = wy0 * (wx0 * d00 + wx1 * d10) + wy1 * (wx0 * d01 + wx1 * d11);
        out[(size_t)(b * 324 + lvl * 81 + o) * HW_ + yx] = v;
      }
    }
    __syncthreads();
  }
}

extern "C" void kernel_launch(void* const* d_in, const int* in_sizes, int n_in,
                              void* d_out, int out_size, void* d_ws, size_t ws_size,
                              hipStream_t stream) {
  (void)in_sizes; (void)n_in; (void)out_size; (void)ws_size;
  const float* f1   = (const float*)d_in[0];
  const float* f2   = (const float*)d_in[1];
  const float* cent = (const float*)d_in[2];
  float* out = (float*)d_out;

  char* ws = (char*)d_ws;
  _Float16* f1t = (_Float16*)(ws + F1OFF);
  _Float16* L0  = (_Float16*)(ws + L0OFF);
  _Float16* L1  = (_Float16*)(ws + L1OFF);
  _Float16* L2  = (_Float16*)(ws + L2OFF);
  _Float16* L3  = (_Float16*)(ws + L3OFF);

  hipMemsetAsync(d_ws, 0, 512, stream);  // zero page for OOB gathers

  dim3 tb(32, 8, 1);
  dim3 tg(HW_ / 32, C_ / 32, B_);
  hipLaunchKernelGGL(k_transpose, tg, tb, 0, stream, f1, f1t, 0.0625f);
  hipLaunchKernelGGL(k_transpose, tg, tb, 0, stream, f2, L0, 1.0f);
  hipLaunchKernelGGL(k_pool, dim3(B_ * 48 * 48), dim3(256), 0, stream, L0, L1, 96, 96);
  hipLaunchKernelGGL(k_pool, dim3(B_ * 24 * 24), dim3(256), 0, stream, L1, L2, 48, 48);
  hipLaunchKernelGGL(k_pool, dim3(B_ * 12 * 12), dim3(256), 0, stream, L2, L3, 24, 24);
  hipLaunchKernelGGL(k_corr, dim3(B_ * HW_ / 4), dim3(256), 0, stream, ws, cent, out);
}

// Round 3
// 190.121 us; speedup vs baseline: 1.0031x; 1.0031x over previous
//
#include <hip/hip_runtime.h>
#include <hip/hip_bf16.h>
#include <stdint.h>

#define B_ 2
#define C_ 256
#define H_ 96
#define W_ 96
#define HW_ (H_*W_)

typedef _Float16 h2 __attribute__((ext_vector_type(2)));
typedef _Float16 h8 __attribute__((ext_vector_type(8)));

union H8U { h8 v; h2 h[4]; };

__device__ __forceinline__ float dot2f(h2 a, h2 b, float c) {
#if __has_builtin(__builtin_amdgcn_fdot2)
  return __builtin_amdgcn_fdot2(a, b, c, false);
#else
  return c + (float)a[0] * (float)b[0] + (float)a[1] * (float)b[1];
#endif
}

// ---------- (B, C, HW) f32  ->  (B, HW, C) f16 tile transpose (+scale) ----------
__global__ __launch_bounds__(256) void k_transpose(const float* __restrict__ in,
                                                   _Float16* __restrict__ out,
                                                   float scale) {
  __shared__ float t[32][33];
  const int b = blockIdx.z;
  const int p0 = blockIdx.x * 32, c0 = blockIdx.y * 32;
  const int tx = threadIdx.x, ty = threadIdx.y;
  const float* src = in + ((size_t)b * C_ + c0) * HW_ + p0;
#pragma unroll
  for (int i = 0; i < 4; ++i)
    t[ty + 8 * i][tx] = src[(size_t)(ty + 8 * i) * HW_ + tx];
  __syncthreads();
  _Float16* dst = out + ((size_t)b * HW_ + p0) * C_ + c0;
#pragma unroll
  for (int i = 0; i < 4; ++i)
    dst[(size_t)(ty + 8 * i) * C_ + tx] = (_Float16)(t[tx][ty + 8 * i] * scale);
}

// ---------- 2x2 avg pool on (B, h, w, C) f16 ----------
__global__ __launch_bounds__(256) void k_pool(const _Float16* __restrict__ in,
                                              _Float16* __restrict__ out,
                                              int hin, int win) {
  const int wout = win >> 1, hout = hin >> 1;
  int idx = blockIdx.x;
  const int X = idx % wout; idx /= wout;
  const int Y = idx % hout; const int b = idx / hout;
  const int c = threadIdx.x;
  const _Float16* p = in + (((size_t)b * hin + 2 * Y) * win + 2 * X) * C_ + c;
  const size_t rs = (size_t)win * C_;
  float v = (float)p[0] + (float)p[C_] + (float)p[rs] + (float)p[rs + C_];
  out[(((size_t)b * hout + Y) * wout + X) * C_ + c] = (_Float16)(v * 0.25f);
}

// workspace byte layout: [zero page 512][f1t][L0][L1][L2][L3]
#define F1OFF 512u
#define L0OFF 9437696u
#define L1OFF 18874880u
#define L2OFF 21234176u
#define L3OFF 21824000u

#define DOT16(r, u0, u1, u2, u3, base)                                   \
  do {                                                                   \
    float q0 = 0.f, q1 = 0.f, q2 = 0.f, q3 = 0.f;                        \
    q0 = dot2f(u0.h[0], f1h[0],  q0); q0 = dot2f(u0.h[1], f1h[1],  q0);  \
    q0 = dot2f(u0.h[2], f1h[2],  q0); q0 = dot2f(u0.h[3], f1h[3],  q0);  \
    q1 = dot2f(u1.h[0], f1h[4],  q1); q1 = dot2f(u1.h[1], f1h[5],  q1);  \
    q1 = dot2f(u1.h[2], f1h[6],  q1); q1 = dot2f(u1.h[3], f1h[7],  q1);  \
    q2 = dot2f(u2.h[0], f1h[8],  q2); q2 = dot2f(u2.h[1], f1h[9],  q2);  \
    q2 = dot2f(u2.h[2], f1h[10], q2); q2 = dot2f(u2.h[3], f1h[11], q2);  \
    q3 = dot2f(u3.h[0], f1h[12], q3); q3 = dot2f(u3.h[1], f1h[13], q3);  \
    q3 = dot2f(u3.h[2], f1h[14], q3); q3 = dot2f(u3.h[3], f1h[15], q3);  \
    r = (q0 + q1) + (q2 + q3);                                           \
  } while (0)

// ---------- main: per-pixel windowed dot products + bilinear combine ----------
__global__ __launch_bounds__(256, 4) void k_corr(const char* __restrict__ ws,
                                                 const float* __restrict__ cent,
                                                 float* __restrict__ out) {
  __shared__ float dl[4][112];
  __shared__ uint32_t ofs[4][112];
  const int wid  = threadIdx.x >> 6;
  const int lane = threadIdx.x & 63;
  const int cg   = lane & 7;           // channel subgroup (32 ch = 4x h8)
  const int pg   = lane >> 3;          // position subgroup

  // XCD-aware swizzle: XCDs 0-3 -> batch 0, XCDs 4-7 -> batch 1.
  const int g    = blockIdx.x;
  const int xcd  = g & 7;
  const int slot = g >> 3;
  const int b    = xcd >> 2;
  const int ib   = slot * 4 + (xcd & 3);
  const int yx   = ib * 4 + wid;
  const int pix  = b * HW_ + yx;

  const float cx = cent[(size_t)(b * 2 + 0) * HW_ + yx];
  const float cy = cent[(size_t)(b * 2 + 1) * HW_ + yx];

  // f1 (pre-scaled by 1/16 in transpose) as 16 packed h2 regs
  h2 f1h[16];
  {
    const h8* fp = (const h8*)(ws + F1OFF + (size_t)pix * 512 + cg * 16);
#pragma unroll
    for (int it = 0; it < 4; ++it) {
      H8U u; u.v = fp[it * 8];
      f1h[it * 4 + 0] = u.h[0]; f1h[it * 4 + 1] = u.h[1];
      f1h[it * 4 + 2] = u.h[2]; f1h[it * 4 + 3] = u.h[3];
    }
  }

  constexpr uint32_t LB[4] = {L0OFF, L1OFF, L2OFF, L3OFF};
  constexpr uint32_t PB[4] = {4718592u, 1179648u, 294912u, 73728u};

#pragma unroll
  for (int lvl = 0; lvl < 4; ++lvl) {
    const int hl = H_ >> lvl, wl = W_ >> lvl;
    const float sc  = 1.0f / (float)(1 << lvl);
    const float cxl = cx * sc, cyl = cy * sc;
    const float fx = floorf(cxl), fy = floorf(cyl);
    const int X0 = (int)fx - 4, Y0 = (int)fy - 4;
    const float wx1 = cxl - fx, wy1 = cyl - fy;
    const float wx0 = 1.0f - wx1, wy0 = 1.0f - wy1;

    // build per-wave offset table: 100 positions (+12 phantom -> zero page)
    const uint32_t lbase = LB[lvl] + (uint32_t)b * PB[lvl];
#pragma unroll
    for (int r = 0; r < 2; ++r) {
      const int p = r * 64 + lane;
      if (p < 112) {
        const int prow = p / 10, pcol = p - prow * 10;
        const int yy = Y0 + prow, xx = X0 + pcol;
        const bool valid = (p < 100) & (yy >= 0) & (yy < hl) & (xx >= 0) & (xx < wl);
        ofs[wid][p] = valid ? (lbase + ((uint32_t)(yy * wl + xx) << 9)) : 0u;
      }
    }
    __syncthreads();

    // 112 slots, 16 per double-iteration: 8 dwordx4 loads in flight per wave
    for (int it = 0; it < 7; ++it) {
      const int pA = it * 16 + pg, pB = pA + 8;
      const uint32_t offA = ofs[wid][pA] + (uint32_t)cg * 16;
      const uint32_t offB = ofs[wid][pB] + (uint32_t)cg * 16;
      const h8* hpA = (const h8*)(ws + offA);
      const h8* hpB = (const h8*)(ws + offB);
      H8U a0, a1, a2, a3, b0, b1, b2, b3;
      a0.v = hpA[0]; a1.v = hpA[8]; a2.v = hpA[16]; a3.v = hpA[24];
      b0.v = hpB[0]; b1.v = hpB[8]; b2.v = hpB[16]; b3.v = hpB[24];
      float accA, accB;
      DOT16(accA, a0, a1, a2, a3, f1h);
      DOT16(accB, b0, b1, b2, b3, f1h);
      accA += __shfl_xor(accA, 1);
      accB += __shfl_xor(accB, 1);
      accA += __shfl_xor(accA, 2);
      accB += __shfl_xor(accB, 2);
      accA += __shfl_xor(accA, 4);
      accB += __shfl_xor(accB, 4);
      if (cg == 0) {
        if (pA < 100) dl[wid][pA] = accA;
        if (pB < 100) dl[wid][pB] = accB;
      }
    }
    __syncthreads();

    // separable bilinear combine + store
#pragma unroll
    for (int r = 0; r < 2; ++r) {
      const int o = r * 64 + lane;
      if (o < 81) {
        const int a = o / 9, bq = o - a * 9;
        const float* d = dl[wid];
        const float d00 = d[bq * 10 + a],      d10 = d[bq * 10 + a + 1];
        const float d01 = d[bq * 10 + a + 10], d11 = d[bq * 10 + a + 11];
        const float v = wy0 * (wx0 * d00 + wx1 * d10) + wy1 * (wx0 * d01 + wx1 * d11);
        out[(size_t)(b * 324 + lvl * 81 + o) * HW_ + yx] = v;
      }
    }
    __syncthreads();
  }
}

extern "C" void kernel_launch(void* const* d_in, const int* in_sizes, int n_in,
                              void* d_out, int out_size, void* d_ws, size_t ws_size,
                              hipStream_t stream) {
  (void)in_sizes; (void)n_in; (void)out_size; (void)ws_size;
  const float* f1   = (const float*)d_in[0];
  const float* f2   = (const float*)d_in[1];
  const float* cent = (const float*)d_in[2];
  float* out = (float*)d_out;

  char* ws = (char*)d_ws;
  _Float16* f1t = (_Float16*)(ws + F1OFF);
  _Float16* L0  = (_Float16*)(ws + L0OFF);
  _Float16* L1  = (_Float16*)(ws + L1OFF);
  _Float16* L2  = (_Float16*)(ws + L2OFF);
  _Float16* L3  = (_Float16*)(ws + L3OFF);

  hipMemsetAsync(d_ws, 0, 512, stream);  // zero page for OOB gathers

  dim3 tb(32, 8, 1);
  dim3 tg(HW_ / 32, C_ / 32, B_);
  hipLaunchKernelGGL(k_transpose, tg, tb, 0, stream, f1, f1t, 0.0625f);
  hipLaunchKernelGGL(k_transpose, tg, tb, 0, stream, f2, L0, 1.0f);
  hipLaunchKernelGGL(k_pool, dim3(B_ * 48 * 48), dim3(256), 0, stream, L0, L1, 96, 96);
  hipLaunchKernelGGL(k_pool, dim3(B_ * 24 * 24), dim3(256), 0, stream, L1, L2, 48, 48);
  hipLaunchKernelGGL(k_pool, dim3(B_ * 12 * 12), dim3(256), 0, stream, L2, L3, 24, 24);
  hipLaunchKernelGGL(k_corr, dim3(B_ * HW_ / 4), dim3(256), 0, stream, ws, cent, out);
}